// Round 14
// baseline (220.136 us; speedup 1.0000x reference)
//
#include <hip/hip_runtime.h>
#include <hip/hip_bf16.h>
#include <cstdint>
#include <cstddef>

using fx4  = __attribute__((ext_vector_type(4))) float;
using bfx8 = __attribute__((ext_vector_type(8))) short;
using sx4  = __attribute__((ext_vector_type(4))) short;

#define DEV __device__ __forceinline__

static constexpr int BATCH = 64;
static constexpr int NTOK  = 197;
static constexpr int NH    = 12;
static constexpr int HD    = 64;
static constexpr int MROWS = BATCH * NTOK;   // 12608
static constexpr int MPAD  = 12800;          // covers 99*128 = 12672
static constexpr int KDIM  = 768;

DEV unsigned short f2bf(float f) {
  unsigned u = __builtin_bit_cast(unsigned, f);
  u += 0x7FFFu + ((u >> 16) & 1u);
  return (unsigned short)(u >> 16);
}

DEV void gload16(const unsigned short* g, unsigned short* l) {
  __builtin_amdgcn_global_load_lds(
      (const __attribute__((address_space(1))) unsigned int*)g,
      (__attribute__((address_space(3))) unsigned int*)l, 16, 0, 0);
}

// Bijective XCD-aware block remap (m204).
DEV int xcd_swizzle(int orig, int nwg) {
  int q = nwg >> 3, r = nwg & 7;
  int xcd = orig & 7, lid = orig >> 3;
  return (xcd < r ? xcd * (q + 1) : r * (q + 1) + (xcd - r) * q) + lid;
}

// ---------------------------------------------------------------------------
// rpb[h][i][j] = rpb_high[h_index[i,j], h] + rpb_width[w_index[i,j], h]
// ---------------------------------------------------------------------------
__global__ void rpb_kernel(const float* __restrict__ rh, const float* __restrict__ rw,
                           const int* __restrict__ hidx, const int* __restrict__ widx,
                           float* __restrict__ rpb)
{
  int e = blockIdx.x * 256 + threadIdx.x;
  const int NN = NTOK * NTOK;
  if (e >= NH * NN) return;
  int h = e / NN, ij = e % NN;
  rpb[e] = rh[hidx[ij] * NH + h] + rw[widx[ij] * NH + h];
}

// ---------------------------------------------------------------------------
// Elementwise fp32 -> bf16. Pads [nvec, nvec_pad) with zeros. (fx4 granules)
// ---------------------------------------------------------------------------
__global__ void cvt_kernel(const float* __restrict__ in,
                           unsigned short* __restrict__ out,
                           int nvec, int nvec_pad)
{
  for (int v = blockIdx.x * 256 + threadIdx.x; v < nvec_pad; v += gridDim.x * 256) {
    fx4 x = (v < nvec) ? ((const fx4*)in)[v] : fx4{0.f, 0.f, 0.f, 0.f};
    sx4 h4;
    #pragma unroll
    for (int q = 0; q < 4; q++) h4[q] = (short)f2bf(x[q]);
    ((sx4*)out)[v] = h4;
  }
}

// ---------------------------------------------------------------------------
// bf16 MFMA GEMM, counted-vmcnt 2-phase pipeline (T3/T4 minimum form):
// C[M,N] = A[M,K] @ B[N,K]^T, K=768, BK=64, 128x128 tile, 4 waves (2x2,
// 64x64 each), double-buffered 64 KB LDS, global_load_lds staging with the
// XOR granule swizzle verified in round 13 (source (l&7)^((l>>3)&7), read
// (ks*4+g)^(fr&7)). Loop: vmcnt(8) -> barrier -> compute -> barrier ->
// STAGE(kt+2). Next tile's loads stay in flight across compute; no drain-0
// in steady state. Ledger: 8 loads/stage, prologue 16 outstanding.
// MODE 0: qkv epilogue -> q/k/v bf16 [B,H,N,hd] (bias + 0.125 scale on q)
// MODE 1: proj epilogue -> out fp32 (+bias)
// ---------------------------------------------------------------------------
template<int NT, int MODE>
__global__ __launch_bounds__(256, 2)
void gemm_bf16_kernel(const unsigned short* __restrict__ A,
                      const unsigned short* __restrict__ B,
                      const float* __restrict__ bias0, const float* __restrict__ bias1,
                      unsigned short* __restrict__ qb, unsigned short* __restrict__ kb,
                      unsigned short* __restrict__ vb, float* __restrict__ outp)
{
  __shared__ unsigned short At[2][128 * 64];   // 16 KB each
  __shared__ unsigned short Bt[2][128 * 64];   // total 64 KB

  const int t  = threadIdx.x;
  const int w  = t >> 6, l = t & 63;
  const int wr = w >> 1, wc = w & 1;
  const int fr = l & 15, g = l >> 4;
  const int bid = xcd_swizzle(blockIdx.x, gridDim.x);
  const int bm = bid / NT, bn = bid % NT;

  // staging: 16B granules, 8 per 64-short row. round rd covers 32 rows.
  //   row = rd*32 + w*8 + (l>>3); source col-granule = (l&7) ^ ((l>>3)&7)
  //   (row&7 == (l>>3)&7); dest = wave base + lane*16B (linear).
  const int srow = w * 8 + (l >> 3);
  const int sgr8 = ((l & 7) ^ ((l >> 3) & 7)) * 8;

  auto STAGE = [&](int kt, int c) {          // 8 gload16 per thread
    const int k0 = kt * 64;
    #pragma unroll
    for (int rd = 0; rd < 4; rd++) {
      int arow = bm * 128 + rd * 32 + srow;
      gload16(A + (size_t)arow * KDIM + k0 + sgr8, &At[c][(rd * 256 + w * 64) * 8]);
    }
    #pragma unroll
    for (int rd = 0; rd < 4; rd++) {
      int brow = bn * 128 + rd * 32 + srow;
      gload16(B + (size_t)brow * KDIM + k0 + sgr8, &Bt[c][(rd * 256 + w * 64) * 8]);
    }
  };

  fx4 acc[4][4];
  #pragma unroll
  for (int i = 0; i < 4; i++)
    #pragma unroll
    for (int j = 0; j < 4; j++) acc[i][j] = fx4{0.f, 0.f, 0.f, 0.f};

  const int a_r0 = wr * 64 + fr;   // + i*16 (i*16 % 8 == 0 -> row&7 == fr&7)
  const int b_r0 = wc * 64 + fr;   // + j*16
  const int swz7 = fr & 7;

  STAGE(0, 0);                     // 8 outstanding
  STAGE(1, 1);                     // 16 outstanding

  #pragma unroll 1
  for (int kt = 0; kt < 12; kt++) {
    const int c = kt & 1;
    if (kt < 11) asm volatile("s_waitcnt vmcnt(8)" ::: "memory");
    else         asm volatile("s_waitcnt vmcnt(0)" ::: "memory");
    __builtin_amdgcn_s_barrier();            // tile kt fully in LDS, all waves
    asm volatile("" ::: "memory");

    #pragma unroll
    for (int ks = 0; ks < 2; ks++) {
      const int gsw = ((ks * 4 + g) ^ swz7) * 8;
      bfx8 fb[4];
      #pragma unroll
      for (int j = 0; j < 4; j++)
        fb[j] = *(const bfx8*)&Bt[c][(b_r0 + j * 16) * 64 + gsw];
      #pragma unroll
      for (int i = 0; i < 4; i++) {
        bfx8 fa = *(const bfx8*)&At[c][(a_r0 + i * 16) * 64 + gsw];
        #pragma unroll
        for (int j = 0; j < 4; j++)
          acc[i][j] = __builtin_amdgcn_mfma_f32_16x16x32_bf16(fa, fb[j], acc[i][j], 0, 0, 0);
      }
    }

    asm volatile("s_waitcnt lgkmcnt(0)" ::: "memory");
    __builtin_amdgcn_sched_barrier(0);
    __builtin_amdgcn_s_barrier();            // all waves done reading buf c
    asm volatile("" ::: "memory");
    if (kt + 2 < 12) STAGE(kt + 2, c);       // overwrite buf c; +8 in flight
  }

  // epilogue: within frag, row = 4*(l>>4)+reg, col = l&15 (verified layout)
  #pragma unroll
  for (int i = 0; i < 4; i++) {
    #pragma unroll
    for (int j = 0; j < 4; j++) {
      #pragma unroll
      for (int r = 0; r < 4; r++) {
        int row = bm * 128 + wr * 64 + i * 16 + g * 4 + r;
        int col = bn * 128 + wc * 64 + j * 16 + fr;
        if (row >= MROWS) continue;
        float v = acc[i][j][r];
        if (MODE == 0) {
          int which = col / 768;
          int hh = (col >> 6) % 12;
          int d  = col & 63;
          int b  = row / NTOK, n = row % NTOK;
          size_t o = (((size_t)(b * NH + hh)) * NTOK + n) * HD + d;
          if (which == 0)      qb[o] = f2bf((v + bias0[col]) * 0.125f);
          else if (which == 1) kb[o] = f2bf(v);
          else                 vb[o] = f2bf(v + bias1[col - 1536]);
        } else {
          outp[(size_t)row * 768 + col] = v + bias0[col];
        }
      }
    }
  }
}

// ---------------------------------------------------------------------------
// MFMA attention (round-12 verified). Block = (b, h, qt); 4 waves.
// rpb preloaded as MFMA C-init; Q direct global->reg; async V staging.
// ---------------------------------------------------------------------------
__global__ __launch_bounds__(256)
void attn_mfma_kernel(const unsigned short* __restrict__ qf,
                      const unsigned short* __restrict__ kf,
                      const unsigned short* __restrict__ vf,
                      const float* __restrict__ rpb,
                      unsigned short* __restrict__ of)
{
  __shared__ union {
    short Kb[224 * 72];                                   // 32256 B
    struct { short Pb[64 * 232]; short Vt[32 * 232]; } p; // 44544 B
  } u;

  const int t  = threadIdx.x;
  const int w  = t >> 6, l = t & 63;
  const int fr = l & 15, g = l >> 4;
  const int bx = xcd_swizzle(blockIdx.x, BATCH * NH * 4);
  const int b  = bx / (NH * 4);
  const int h  = (bx / 4) % NH;
  const int qt = bx & 3;
  const size_t base = ((size_t)(b * NH + h)) * NTOK * HD;
  const unsigned short* qg = qf + base;
  const unsigned short* kg = kf + base;
  const unsigned short* vg = vf + base;
  const float* rhb = rpb + (size_t)h * (NTOK * NTOK);

  const bfx8 z8 = bfx8{0,0,0,0,0,0,0,0};
  const int qrow0 = qt * 64 + w * 16 + g * 4;

  // ---- rpb preload directly into the MFMA accumulators (issued first)
  fx4 sc[14];
  #pragma unroll
  for (int j = 0; j < 14; j++) {
    int key = j * 16 + fr;
    #pragma unroll
    for (int r = 0; r < 4; r++) {
      int qrow = qrow0 + r;
      sc[j][r] = (key < NTOK && qrow < NTOK) ? rhb[qrow * NTOK + key] : 0.f;
    }
  }

  // ---- Q fragments direct from global
  const int qrow_f = qt * 64 + w * 16 + fr;
  bfx8 aq0 = z8, aq1 = z8;
  if (qrow_f < NTOK) {
    aq0 = *(const bfx8*)(qg + (size_t)qrow_f * HD + g * 8);
    aq1 = *(const bfx8*)(qg + (size_t)qrow_f * HD + 32 + g * 8);
  }

  // ---- async V staging: load half into regs early, LDS-write late
  sx4 vreg[7];
  auto VLOAD = [&](int hf) {
    #pragma unroll
    for (int rep = 0; rep < 7; rep++) {
      int task = rep * 256 + t;     // 0..1791
      int m  = task >> 3;           // 0..223
      int dq = task & 7;            // d-quad within 32-d half
      vreg[rep] = (m < NTOK)
          ? *(const sx4*)(vg + (size_t)m * HD + hf * 32 + dq * 4)
          : sx4{0, 0, 0, 0};
    }
  };
  auto VWRITE = [&]() {
    #pragma unroll
    for (int rep = 0; rep < 7; rep++) {
      int task = rep * 256 + t;
      int m  = task >> 3;
      int dq = task & 7;
      #pragma unroll
      for (int q2 = 0; q2 < 4; q2++)
        u.p.Vt[(dq * 4 + q2) * 232 + m] = vreg[rep][q2];
    }
  };

  VLOAD(0);   // half-0 V loads in flight under K staging + QK^T

  // ---- stage K (224 rows, zero-padded), stride 72
  {
    const int rr = t >> 3, c8 = (t & 7) * 8;
    #pragma unroll
    for (int p = 0; p < 7; p++) {
      int r = p * 32 + rr;
      bfx8 o8 = (r < NTOK) ? *(const bfx8*)(kg + (size_t)r * HD + c8) : z8;
      *(bfx8*)&u.Kb[r * 72 + c8] = o8;
    }
  }
  __syncthreads();

  // ---- QK^T (C-in = rpb)
  #pragma unroll
  for (int j = 0; j < 14; j++) {
    bfx8 k0 = *(const bfx8*)&u.Kb[(j * 16 + fr) * 72 + g * 8];
    bfx8 k1 = *(const bfx8*)&u.Kb[(j * 16 + fr) * 72 + 32 + g * 8];
    sc[j] = __builtin_amdgcn_mfma_f32_16x16x32_bf16(aq0, k0, sc[j], 0, 0, 0);
    sc[j] = __builtin_amdgcn_mfma_f32_16x16x32_bf16(aq1, k1, sc[j], 0, 0, 0);
  }

  // ---- key mask (only frags 12,13 touch keys >= 197)
  #pragma unroll
  for (int j = 12; j < 14; j++) {
    int key = j * 16 + fr;
    if (key >= NTOK) {
      #pragma unroll
      for (int r = 0; r < 4; r++) sc[j][r] = -1e30f;
    }
  }

  // ---- softmax per row (16-lane fr group); unnormalized exp + inv4[r]
  float inv4[4];
  #pragma unroll
  for (int r = 0; r < 4; r++) {
    float m = sc[0][r];
    #pragma unroll
    for (int j = 1; j < 14; j++) m = fmaxf(m, sc[j][r]);
    #pragma unroll
    for (int off = 1; off < 16; off <<= 1) m = fmaxf(m, __shfl_xor(m, off));
    float sum = 0.f;
    #pragma unroll
    for (int j = 0; j < 14; j++) {
      float e = __expf(sc[j][r] - m);
      sc[j][r] = e; sum += e;
    }
    #pragma unroll
    for (int off = 1; off < 16; off <<= 1) sum += __shfl_xor(sum, off);
    inv4[r] = 1.0f / sum;
  }

  __syncthreads();   // B1: all Kb reads complete -> union reuse safe

  // ---- P write (unnormalized bf16)
  #pragma unroll
  for (int j = 0; j < 14; j++) {
    int key = j * 16 + fr;
    #pragma unroll
    for (int r = 0; r < 4; r++)
      u.p.Pb[(w * 16 + g * 4 + r) * 232 + key] = (short)f2bf(sc[j][r]);
  }
  VWRITE();          // half-0
  __syncthreads();   // B2: P + Vt half-0 staged

  fx4 o2[4];
  #pragma unroll
  for (int j = 0; j < 4; j++) o2[j] = fx4{0.f, 0.f, 0.f, 0.f};

  VLOAD(1);          // half-1 loads fly under half-0 PV

  #pragma unroll
  for (int kc = 0; kc < 7; kc++) {
    bfx8 pa = *(const bfx8*)&u.p.Pb[(w * 16 + fr) * 232 + kc * 32 + g * 8];
    #pragma unroll
    for (int jj = 0; jj < 2; jj++) {
      bfx8 vbb = *(const bfx8*)&u.p.Vt[(jj * 16 + fr) * 232 + kc * 32 + g * 8];
      o2[jj] = __builtin_amdgcn_mfma_f32_16x16x32_bf16(pa, vbb, o2[jj], 0, 0, 0);
    }
  }

  __syncthreads();   // B3: half-0 Vt reads complete
  VWRITE();          // half-1
  __syncthreads();   // B4: Vt half-1 staged

  #pragma unroll
  for (int kc = 0; kc < 7; kc++) {
    bfx8 pa = *(const bfx8*)&u.p.Pb[(w * 16 + fr) * 232 + kc * 32 + g * 8];
    #pragma unroll
    for (int jj = 0; jj < 2; jj++) {
      bfx8 vbb = *(const bfx8*)&u.p.Vt[(jj * 16 + fr) * 232 + kc * 32 + g * 8];
      o2[2 + jj] = __builtin_amdgcn_mfma_f32_16x16x32_bf16(pa, vbb, o2[2 + jj], 0, 0, 0);
    }
  }

  // ---- normalize + store bf16: q-row w*16+g*4+r, d = j*16+fr
  #pragma unroll
  for (int r = 0; r < 4; r++) {
    int qrow = qt * 64 + w * 16 + g * 4 + r;
    if (qrow < NTOK) {
      float inv = inv4[r];
      #pragma unroll
      for (int j = 0; j < 4; j++)
        of[((size_t)(b * NTOK + qrow)) * 768 + h * 64 + j * 16 + fr]
            = f2bf(o2[j][r] * inv);
    }
  }
}

// ---------------------------------------------------------------------------
extern "C" void kernel_launch(void* const* d_in, const int* in_sizes, int n_in,
                              void* d_out, int out_size, void* d_ws, size_t ws_size,
                              hipStream_t stream)
{
  const float* x      = (const float*)d_in[0];
  const float* qkv_w  = (const float*)d_in[1];
  const float* q_bias = (const float*)d_in[2];
  const float* v_bias = (const float*)d_in[3];
  const float* proj_w = (const float*)d_in[4];
  const float* proj_b = (const float*)d_in[5];
  const float* rpb_h  = (const float*)d_in[6];
  const float* rpb_w  = (const float*)d_in[7];
  const int*   h_idx  = (const int*)d_in[8];
  const int*   w_idx  = (const int*)d_in[9];
  float* out = (float*)d_out;

  char* ws = (char*)d_ws;
  size_t off = 0;
  auto alloc = [&](size_t bytes) { size_t o = off; off += (bytes + 255) & ~(size_t)255; return o; };

  const size_t QKV_ELEMS = (size_t)BATCH * NH * NTOK * HD;
  unsigned short* Axb = (unsigned short*)(ws + alloc((size_t)MPAD * KDIM * 2));
  unsigned short* Bqb = (unsigned short*)(ws + alloc((size_t)2304 * KDIM * 2));
  unsigned short* Bpb = (unsigned short*)(ws + alloc((size_t)768 * KDIM * 2));
  unsigned short* qb  = (unsigned short*)(ws + alloc(QKV_ELEMS * 2));
  unsigned short* kb  = (unsigned short*)(ws + alloc(QKV_ELEMS * 2));
  unsigned short* vb  = (unsigned short*)(ws + alloc(QKV_ELEMS * 2));
  float*          rpb = (float*)(ws + alloc((size_t)NH * NTOK * NTOK * 4));
  unsigned short* ofb = (unsigned short*)(ws + alloc((size_t)MPAD * KDIM * 2));
  (void)ws_size; (void)in_sizes; (void)n_in; (void)out_size;

  const int nvec_x  = MROWS * KDIM / 4;
  const int nvec_xp = MPAD * KDIM / 4;

  // 1) convert inputs to bf16; rpb table; zero pad rows of attn-out buffer
  cvt_kernel<<<2048, 256, 0, stream>>>(x, Axb, nvec_x, nvec_xp);
  cvt_kernel<<<1024, 256, 0, stream>>>(qkv_w, Bqb, 2304 * KDIM / 4, 2304 * KDIM / 4);
  cvt_kernel<<<512, 256, 0, stream>>>(proj_w, Bpb, 768 * KDIM / 4, 768 * KDIM / 4);
  {
    int total = NH * NTOK * NTOK;
    rpb_kernel<<<(total + 255) / 256, 256, 0, stream>>>(rpb_h, rpb_w, h_idx, w_idx, rpb);
  }
  hipMemsetAsync(ofb + (size_t)MROWS * KDIM, 0,
                 (size_t)(MPAD - MROWS) * KDIM * 2, stream);
  // 2) qkv GEMM: 99 x 18 tiles (128x128), 256 threads, dbuf counted-vmcnt
  gemm_bf16_kernel<18, 0><<<99 * 18, 256, 0, stream>>>(
      Axb, Bqb, q_bias, v_bias, qb, kb, vb, nullptr);
  // 3) MFMA attention -> ofb bf16
  attn_mfma_kernel<<<BATCH * NH * 4, 256, 0, stream>>>(qb, kb, vb, rpb, ofb);
  // 4) proj GEMM: 99 x 6 tiles -> out fp32
  gemm_bf16_kernel<6, 1><<<99 * 6, 256, 0, stream>>>(
      ofb, Bpb, proj_b, nullptr, nullptr, nullptr, nullptr, out);
}

// Round 15
// 170.483 us; speedup vs baseline: 1.2913x; 1.2913x over previous
//
#include <hip/hip_runtime.h>
#include <hip/hip_bf16.h>
#include <cstdint>
#include <cstddef>

using fx4  = __attribute__((ext_vector_type(4))) float;
using bfx8 = __attribute__((ext_vector_type(8))) short;
using sx4  = __attribute__((ext_vector_type(4))) short;

#define DEV __device__ __forceinline__

static constexpr int BATCH = 64;
static constexpr int NTOK  = 197;
static constexpr int NH    = 12;
static constexpr int HD    = 64;
static constexpr int MROWS = BATCH * NTOK;   // 12608
static constexpr int MPAD  = 12800;          // 50 * 256
static constexpr int KDIM  = 768;

DEV unsigned short f2bf(float f) {
  unsigned u = __builtin_bit_cast(unsigned, f);
  u += 0x7FFFu + ((u >> 16) & 1u);
  return (unsigned short)(u >> 16);
}

DEV void gload16(const unsigned short* g, unsigned short* l) {
  __builtin_amdgcn_global_load_lds(
      (const __attribute__((address_space(1))) unsigned int*)g,
      (__attribute__((address_space(3))) unsigned int*)l, 16, 0, 0);
}

// Bijective XCD-aware block remap (m204).
DEV int xcd_swizzle(int orig, int nwg) {
  int q = nwg >> 3, r = nwg & 7;
  int xcd = orig & 7, lid = orig >> 3;
  return (xcd < r ? xcd * (q + 1) : r * (q + 1) + (xcd - r) * q) + lid;
}

DEV void cvt_seg(const float* __restrict__ in, unsigned short* __restrict__ out,
                 int nvec, int nvec_pad, int bseg, int nblk, int t)
{
  for (int v = bseg * 256 + t; v < nvec_pad; v += nblk * 256) {
    fx4 x = (v < nvec) ? ((const fx4*)in)[v] : fx4{0.f, 0.f, 0.f, 0.f};
    sx4 h4;
    #pragma unroll
    for (int q = 0; q < 4; q++) h4[q] = (short)f2bf(x[q]);
    ((sx4*)out)[v] = h4;
  }
}

// ---------------------------------------------------------------------------
// Fused prologue: one launch. Segments by blockIdx:
//  [0,2048)    x fp32 -> bf16 (padded to MPAD rows)
//  [2048,2560) qkv_w fp32 -> bf16
//  [2560,2688) proj_w fp32 -> bf16
//  [2688,3200) rpb[h][i][j] = rpb_high[h_index,h] + rpb_width[w_index,h]
//  [3200,3216) zero ofb pad rows
// ---------------------------------------------------------------------------
__global__ __launch_bounds__(256)
void prologue_kernel(const float* __restrict__ x, unsigned short* __restrict__ Axb,
                     const float* __restrict__ qkvw, unsigned short* __restrict__ Bqb,
                     const float* __restrict__ projw, unsigned short* __restrict__ Bpb,
                     const float* __restrict__ rh, const float* __restrict__ rw,
                     const int* __restrict__ hidx, const int* __restrict__ widx,
                     float* __restrict__ rpb, unsigned short* __restrict__ ofb)
{
  const int blk = blockIdx.x, t = threadIdx.x;
  if (blk < 2048) {
    cvt_seg(x, Axb, MROWS * KDIM / 4, MPAD * KDIM / 4, blk, 2048, t);
  } else if (blk < 2560) {
    cvt_seg(qkvw, Bqb, 2304 * KDIM / 4, 2304 * KDIM / 4, blk - 2048, 512, t);
  } else if (blk < 2688) {
    cvt_seg(projw, Bpb, 768 * KDIM / 4, 768 * KDIM / 4, blk - 2560, 128, t);
  } else if (blk < 3200) {
    const int NN = NTOK * NTOK;
    for (int e = (blk - 2688) * 256 + t; e < NH * NN; e += 512 * 256) {
      int h = e / NN, ij = e % NN;
      rpb[e] = rh[hidx[ij] * NH + h] + rw[widx[ij] * NH + h];
    }
  } else {
    sx4* pad = (sx4*)(ofb + (size_t)MROWS * KDIM);
    const int nv = (MPAD - MROWS) * KDIM / 4;
    for (int v = (blk - 3200) * 256 + t; v < nv; v += 16 * 256)
      pad[v] = sx4{0, 0, 0, 0};
  }
}

// ---------------------------------------------------------------------------
// bf16 MFMA GEMM (round-13 verified best): C[M,N] = A[M,K] @ B[N,K]^T,
// K=768, BK=64, 256x128 tile, 8 waves (4M x 2N), 48 KB LDS, gload16 staging
// with XOR granule swizzle (source (l&7)^((l>>3)&7); read (ks*4+g)^(fr&7)).
// 12 K-steps, 2 barriers each. Conflict-free (measured 0).
// MODE 0: qkv epilogue -> q/k/v bf16 [B,H,N,hd] (bias + 0.125 scale on q)
// MODE 1: proj epilogue -> out fp32 (+bias)
// ---------------------------------------------------------------------------
template<int NT, int MODE>
__global__ __launch_bounds__(512, 4)
void gemm_bf16_kernel(const unsigned short* __restrict__ A,
                      const unsigned short* __restrict__ B,
                      const float* __restrict__ bias0, const float* __restrict__ bias1,
                      unsigned short* __restrict__ qb, unsigned short* __restrict__ kb,
                      unsigned short* __restrict__ vb, float* __restrict__ outp)
{
  __shared__ unsigned short At[256 * 64];   // 32 KB
  __shared__ unsigned short Bt[128 * 64];   // 16 KB

  const int t  = threadIdx.x;
  const int w  = t >> 6, l = t & 63;
  const int wr = w >> 1, wc = w & 1;        // 4 M-waves x 2 N-waves
  const int fr = l & 15, g = l >> 4;
  const int bid = xcd_swizzle(blockIdx.x, gridDim.x);
  const int bm = bid / NT, bn = bid % NT;

  const int srow = w * 8 + (l >> 3);
  const int sgr8 = ((l & 7) ^ ((l >> 3) & 7)) * 8;

  auto STAGE = [&](int k0) {
    #pragma unroll
    for (int rd = 0; rd < 4; rd++) {
      int arow = bm * 256 + rd * 64 + srow;
      gload16(A + (size_t)arow * KDIM + k0 + sgr8, &At[(rd * 512 + w * 64) * 8]);
    }
    #pragma unroll
    for (int rd = 0; rd < 2; rd++) {
      int brow = bn * 128 + rd * 64 + srow;
      gload16(B + (size_t)brow * KDIM + k0 + sgr8, &Bt[(rd * 512 + w * 64) * 8]);
    }
  };

  fx4 acc[4][4];
  #pragma unroll
  for (int i = 0; i < 4; i++)
    #pragma unroll
    for (int j = 0; j < 4; j++) acc[i][j] = fx4{0.f, 0.f, 0.f, 0.f};

  const int a_r0 = wr * 64 + fr;
  const int b_r0 = wc * 64 + fr;
  const int swz7 = fr & 7;

  #pragma unroll 1
  for (int kt = 0; kt < 12; kt++) {
    __syncthreads();               // prior reads of LDS complete
    STAGE(kt * 64);
    __syncthreads();               // drains vmcnt: tile ready

    #pragma unroll
    for (int ks = 0; ks < 2; ks++) {
      const int gsw = ((ks * 4 + g) ^ swz7) * 8;
      bfx8 fb[4];
      #pragma unroll
      for (int j = 0; j < 4; j++)
        fb[j] = *(const bfx8*)&Bt[(b_r0 + j * 16) * 64 + gsw];
      #pragma unroll
      for (int i = 0; i < 4; i++) {
        bfx8 fa = *(const bfx8*)&At[(a_r0 + i * 16) * 64 + gsw];
        #pragma unroll
        for (int j = 0; j < 4; j++)
          acc[i][j] = __builtin_amdgcn_mfma_f32_16x16x32_bf16(fa, fb[j], acc[i][j], 0, 0, 0);
      }
    }
  }

  // epilogue: within frag, row = 4*(l>>4)+reg, col = l&15 (verified layout)
  #pragma unroll
  for (int i = 0; i < 4; i++) {
    #pragma unroll
    for (int j = 0; j < 4; j++) {
      #pragma unroll
      for (int r = 0; r < 4; r++) {
        int row = bm * 256 + wr * 64 + i * 16 + g * 4 + r;
        int col = bn * 128 + wc * 64 + j * 16 + fr;
        if (row >= MROWS) continue;
        float v = acc[i][j][r];
        if (MODE == 0) {
          int which = col / 768;
          int hh = (col >> 6) % 12;
          int d  = col & 63;
          int b  = row / NTOK, n = row % NTOK;
          size_t o = (((size_t)(b * NH + hh)) * NTOK + n) * HD + d;
          if (which == 0)      qb[o] = f2bf((v + bias0[col]) * 0.125f);
          else if (which == 1) kb[o] = f2bf(v);
          else                 vb[o] = f2bf(v + bias1[col - 1536]);
        } else {
          outp[(size_t)row * 768 + col] = v + bias0[col];
        }
      }
    }
  }
}

// ---------------------------------------------------------------------------
// MFMA attention (round-12 verified) + setprio around MFMA clusters (T5).
// Block = (b, h, qt); 4 waves. rpb preloaded as MFMA C-init; Q direct
// global->reg; async V staging (load-early/write-late).
// ---------------------------------------------------------------------------
__global__ __launch_bounds__(256)
void attn_mfma_kernel(const unsigned short* __restrict__ qf,
                      const unsigned short* __restrict__ kf,
                      const unsigned short* __restrict__ vf,
                      const float* __restrict__ rpb,
                      unsigned short* __restrict__ of)
{
  __shared__ union {
    short Kb[224 * 72];                                   // 32256 B
    struct { short Pb[64 * 232]; short Vt[32 * 232]; } p; // 44544 B
  } u;

  const int t  = threadIdx.x;
  const int w  = t >> 6, l = t & 63;
  const int fr = l & 15, g = l >> 4;
  const int bx = xcd_swizzle(blockIdx.x, BATCH * NH * 4);
  const int b  = bx / (NH * 4);
  const int h  = (bx / 4) % NH;
  const int qt = bx & 3;
  const size_t base = ((size_t)(b * NH + h)) * NTOK * HD;
  const unsigned short* qg = qf + base;
  const unsigned short* kg = kf + base;
  const unsigned short* vg = vf + base;
  const float* rhb = rpb + (size_t)h * (NTOK * NTOK);

  const bfx8 z8 = bfx8{0,0,0,0,0,0,0,0};
  const int qrow0 = qt * 64 + w * 16 + g * 4;

  // ---- rpb preload directly into the MFMA accumulators (issued first)
  fx4 sc[14];
  #pragma unroll
  for (int j = 0; j < 14; j++) {
    int key = j * 16 + fr;
    #pragma unroll
    for (int r = 0; r < 4; r++) {
      int qrow = qrow0 + r;
      sc[j][r] = (key < NTOK && qrow < NTOK) ? rhb[qrow * NTOK + key] : 0.f;
    }
  }

  // ---- Q fragments direct from global
  const int qrow_f = qt * 64 + w * 16 + fr;
  bfx8 aq0 = z8, aq1 = z8;
  if (qrow_f < NTOK) {
    aq0 = *(const bfx8*)(qg + (size_t)qrow_f * HD + g * 8);
    aq1 = *(const bfx8*)(qg + (size_t)qrow_f * HD + 32 + g * 8);
  }

  // ---- async V staging: load half into regs early, LDS-write late
  sx4 vreg[7];
  auto VLOAD = [&](int hf) {
    #pragma unroll
    for (int rep = 0; rep < 7; rep++) {
      int task = rep * 256 + t;     // 0..1791
      int m  = task >> 3;           // 0..223
      int dq = task & 7;            // d-quad within 32-d half
      vreg[rep] = (m < NTOK)
          ? *(const sx4*)(vg + (size_t)m * HD + hf * 32 + dq * 4)
          : sx4{0, 0, 0, 0};
    }
  };
  auto VWRITE = [&]() {
    #pragma unroll
    for (int rep = 0; rep < 7; rep++) {
      int task = rep * 256 + t;
      int m  = task >> 3;
      int dq = task & 7;
      #pragma unroll
      for (int q2 = 0; q2 < 4; q2++)
        u.p.Vt[(dq * 4 + q2) * 232 + m] = vreg[rep][q2];
    }
  };

  VLOAD(0);   // half-0 V loads in flight under K staging + QK^T

  // ---- stage K (224 rows, zero-padded), stride 72
  {
    const int rr = t >> 3, c8 = (t & 7) * 8;
    #pragma unroll
    for (int p = 0; p < 7; p++) {
      int r = p * 32 + rr;
      bfx8 o8 = (r < NTOK) ? *(const bfx8*)(kg + (size_t)r * HD + c8) : z8;
      *(bfx8*)&u.Kb[r * 72 + c8] = o8;
    }
  }
  __syncthreads();

  // ---- QK^T (C-in = rpb)
  __builtin_amdgcn_s_setprio(1);
  #pragma unroll
  for (int j = 0; j < 14; j++) {
    bfx8 k0 = *(const bfx8*)&u.Kb[(j * 16 + fr) * 72 + g * 8];
    bfx8 k1 = *(const bfx8*)&u.Kb[(j * 16 + fr) * 72 + 32 + g * 8];
    sc[j] = __builtin_amdgcn_mfma_f32_16x16x32_bf16(aq0, k0, sc[j], 0, 0, 0);
    sc[j] = __builtin_amdgcn_mfma_f32_16x16x32_bf16(aq1, k1, sc[j], 0, 0, 0);
  }
  __builtin_amdgcn_s_setprio(0);

  // ---- key mask (only frags 12,13 touch keys >= 197)
  #pragma unroll
  for (int j = 12; j < 14; j++) {
    int key = j * 16 + fr;
    if (key >= NTOK) {
      #pragma unroll
      for (int r = 0; r < 4; r++) sc[j][r] = -1e30f;
    }
  }

  // ---- softmax per row (16-lane fr group); unnormalized exp + inv4[r]
  float inv4[4];
  #pragma unroll
  for (int r = 0; r < 4; r++) {
    float m = sc[0][r];
    #pragma unroll
    for (int j = 1; j < 14; j++) m = fmaxf(m, sc[j][r]);
    #pragma unroll
    for (int off = 1; off < 16; off <<= 1) m = fmaxf(m, __shfl_xor(m, off));
    float sum = 0.f;
    #pragma unroll
    for (int j = 0; j < 14; j++) {
      float e = __expf(sc[j][r] - m);
      sc[j][r] = e; sum += e;
    }
    #pragma unroll
    for (int off = 1; off < 16; off <<= 1) sum += __shfl_xor(sum, off);
    inv4[r] = 1.0f / sum;
  }

  __syncthreads();   // B1: all Kb reads complete -> union reuse safe

  // ---- P write (unnormalized bf16)
  #pragma unroll
  for (int j = 0; j < 14; j++) {
    int key = j * 16 + fr;
    #pragma unroll
    for (int r = 0; r < 4; r++)
      u.p.Pb[(w * 16 + g * 4 + r) * 232 + key] = (short)f2bf(sc[j][r]);
  }
  VWRITE();          // half-0
  __syncthreads();   // B2: P + Vt half-0 staged

  fx4 o2[4];
  #pragma unroll
  for (int j = 0; j < 4; j++) o2[j] = fx4{0.f, 0.f, 0.f, 0.f};

  VLOAD(1);          // half-1 loads fly under half-0 PV

  __builtin_amdgcn_s_setprio(1);
  #pragma unroll
  for (int kc = 0; kc < 7; kc++) {
    bfx8 pa = *(const bfx8*)&u.p.Pb[(w * 16 + fr) * 232 + kc * 32 + g * 8];
    #pragma unroll
    for (int jj = 0; jj < 2; jj++) {
      bfx8 vbb = *(const bfx8*)&u.p.Vt[(jj * 16 + fr) * 232 + kc * 32 + g * 8];
      o2[jj] = __builtin_amdgcn_mfma_f32_16x16x32_bf16(pa, vbb, o2[jj], 0, 0, 0);
    }
  }
  __builtin_amdgcn_s_setprio(0);

  __syncthreads();   // B3: half-0 Vt reads complete
  VWRITE();          // half-1
  __syncthreads();   // B4: Vt half-1 staged

  __builtin_amdgcn_s_setprio(1);
  #pragma unroll
  for (int kc = 0; kc < 7; kc++) {
    bfx8 pa = *(const bfx8*)&u.p.Pb[(w * 16 + fr) * 232 + kc * 32 + g * 8];
    #pragma unroll
    for (int jj = 0; jj < 2; jj++) {
      bfx8 vbb = *(const bfx8*)&u.p.Vt[(jj * 16 + fr) * 232 + kc * 32 + g * 8];
      o2[2 + jj] = __builtin_amdgcn_mfma_f32_16x16x32_bf16(pa, vbb, o2[2 + jj], 0, 0, 0);
    }
  }
  __builtin_amdgcn_s_setprio(0);

  // ---- normalize + store bf16: q-row w*16+g*4+r, d = j*16+fr
  #pragma unroll
  for (int r = 0; r < 4; r++) {
    int qrow = qt * 64 + w * 16 + g * 4 + r;
    if (qrow < NTOK) {
      float inv = inv4[r];
      #pragma unroll
      for (int j = 0; j < 4; j++)
        of[((size_t)(b * NTOK + qrow)) * 768 + h * 64 + j * 16 + fr]
            = f2bf(o2[j][r] * inv);
    }
  }
}

// ---------------------------------------------------------------------------
extern "C" void kernel_launch(void* const* d_in, const int* in_sizes, int n_in,
                              void* d_out, int out_size, void* d_ws, size_t ws_size,
                              hipStream_t stream)
{
  const float* x      = (const float*)d_in[0];
  const float* qkv_w  = (const float*)d_in[1];
  const float* q_bias = (const float*)d_in[2];
  const float* v_bias = (const float*)d_in[3];
  const float* proj_w = (const float*)d_in[4];
  const float* proj_b = (const float*)d_in[5];
  const float* rpb_h  = (const float*)d_in[6];
  const float* rpb_w  = (const float*)d_in[7];
  const int*   h_idx  = (const int*)d_in[8];
  const int*   w_idx  = (const int*)d_in[9];
  float* out = (float*)d_out;

  char* ws = (char*)d_ws;
  size_t off = 0;
  auto alloc = [&](size_t bytes) { size_t o = off; off += (bytes + 255) & ~(size_t)255; return o; };

  const size_t QKV_ELEMS = (size_t)BATCH * NH * NTOK * HD;
  unsigned short* Axb = (unsigned short*)(ws + alloc((size_t)MPAD * KDIM * 2));
  unsigned short* Bqb = (unsigned short*)(ws + alloc((size_t)2304 * KDIM * 2));
  unsigned short* Bpb = (unsigned short*)(ws + alloc((size_t)768 * KDIM * 2));
  unsigned short* qb  = (unsigned short*)(ws + alloc(QKV_ELEMS * 2));
  unsigned short* kb  = (unsigned short*)(ws + alloc(QKV_ELEMS * 2));
  unsigned short* vb  = (unsigned short*)(ws + alloc(QKV_ELEMS * 2));
  float*          rpb = (float*)(ws + alloc((size_t)NH * NTOK * NTOK * 4));
  unsigned short* ofb = (unsigned short*)(ws + alloc((size_t)MPAD * KDIM * 2));
  (void)ws_size; (void)in_sizes; (void)n_in; (void)out_size;

  // 1) fused prologue: cvt x / qkv_w / proj_w, rpb table, ofb pad zero
  prologue_kernel<<<3216, 256, 0, stream>>>(
      x, Axb, qkv_w, Bqb, proj_w, Bpb, rpb_h, rpb_w, h_idx, w_idx, rpb, ofb);
  // 2) qkv GEMM: 50 x 18 tiles (256x128), 512 threads
  gemm_bf16_kernel<18, 0><<<50 * 18, 512, 0, stream>>>(
      Axb, Bqb, q_bias, v_bias, qb, kb, vb, nullptr);
  // 3) MFMA attention -> ofb bf16
  attn_mfma_kernel<<<BATCH * NH * 4, 256, 0, stream>>>(qb, kb, vb, rpb, ofb);
  // 4) proj GEMM: 50 x 6 tiles -> out fp32
  gemm_bf16_kernel<6, 1><<<50 * 6, 512, 0, stream>>>(
      ofb, Bpb, proj_b, nullptr, nullptr, nullptr, nullptr, out);
}